// Round 3
// baseline (761.358 us; speedup 1.0000x reference)
//
#include <hip/hip_runtime.h>

typedef unsigned short u16;
typedef unsigned int u32;

#define N_NODES 20000
#define NE 320000
#define NLAYERS 4
#define NCLASS 40
#define NEG_SLOPE 0.2f
#define LSTRIDE ((NLAYERS + 1) * 128)  // 640 floats per node in X_all/Y_all

typedef __bf16 bf16x8 __attribute__((ext_vector_type(8)));
typedef float f32x4 __attribute__((ext_vector_type(4)));

__device__ inline u16 f2bf(float f) {
    u32 u = __float_as_uint(f);
    return (u16)((u + 0x7fffu + ((u >> 16) & 1u)) >> 16);  // round-nearest-even
}
__device__ inline float bf2f(u16 u) { return __uint_as_float(((u32)u) << 16); }

// ---------------- init: Xbf=bf16(x), X_all[:,0,:]=x, Y_all[:,0,:]=x ----------------
__global__ void k_init(const float* __restrict__ x, u16* __restrict__ Xbf,
                       float* __restrict__ Xall, float* __restrict__ Yall) {
    int t = blockIdx.x * 256 + threadIdx.x;
    if (t >= N_NODES * 128) return;
    float v = x[t];
    Xbf[t] = f2bf(v);
    int n = t >> 7, c = t & 127;
    int ob = n * LSTRIDE + c;  // layer-0 slot
    Xall[ob] = v;
    Yall[ob] = v;
}

// ---------------- Wt[512][128] = bf16(W^T) ----------------
__global__ void k_trans(const float* __restrict__ W, u16* __restrict__ Wt) {
    int t = blockIdx.x * 256 + threadIdx.x;  // 65536 threads
    int k = t >> 9, col = t & 511;
    Wt[col * 128 + k] = f2bf(W[t]);
}

// ---------------- fold attention vectors through W: Vs/Vd[128][4] (f32, exact path) ----------------
__global__ void k_fold(const float* __restrict__ W, const float* __restrict__ att_s,
                       const float* __restrict__ att_d, float* __restrict__ Vs,
                       float* __restrict__ Vd) {
    int t = threadIdx.x;  // 512 threads: t = row*4 + hd
    int row = t >> 2, hd = t & 3;
    float s1 = 0.f, s2 = 0.f;
    for (int c = 0; c < 128; c++) {
        float w = W[row * 512 + hd * 128 + c];
        s1 += w * att_s[hd * 128 + c];
        s2 += w * att_d[hd * 128 + c];
    }
    Vs[t] = s1;
    Vd[t] = s2;
}

// ---------------- CSR build over dst (self loops included) ----------------
__global__ void k_ones(int* __restrict__ counts) {
    int t = blockIdx.x * 256 + threadIdx.x;
    if (t < N_NODES) counts[t] = 1;  // self loop
}
__global__ void k_count(const int* __restrict__ dst, int* __restrict__ counts) {
    int t = blockIdx.x * 256 + threadIdx.x;
    if (t < NE) atomicAdd(&counts[dst[t]], 1);
}
__global__ void k_scan(const int* __restrict__ counts, int* __restrict__ indptr,
                       int* __restrict__ cursor) {
    __shared__ int part[1024];
    int t = threadIdx.x;
    const int CH = 20;  // 1024*20 >= 20000
    int c0 = t * CH;
    int s = 0;
    for (int i = 0; i < CH; i++) {
        int idx = c0 + i;
        if (idx < N_NODES) s += counts[idx];
    }
    part[t] = s;
    __syncthreads();
    for (int off = 1; off < 1024; off <<= 1) {
        int v = 0;
        if (t >= off) v = part[t - off];
        __syncthreads();
        if (t >= off) part[t] += v;
        __syncthreads();
    }
    int ex = (t == 0) ? 0 : part[t - 1];
    for (int i = 0; i < CH; i++) {
        int idx = c0 + i;
        if (idx < N_NODES) {
            indptr[idx] = ex;
            cursor[idx] = ex;
            ex += counts[idx];
        }
    }
    if (t == 1023) indptr[N_NODES] = part[1023];
}
__global__ void k_scatter(const int* __restrict__ src, const int* __restrict__ dst,
                          int* __restrict__ cursor, int* __restrict__ esrc) {
    int t = blockIdx.x * 256 + threadIdx.x;
    if (t >= NE + N_NODES) return;
    int s, d;
    if (t < NE) { s = src[t]; d = dst[t]; }
    else { s = d = t - NE; }
    int pos = atomicAdd(&cursor[d], 1);
    esrc[pos] = s;
}

// ---------------- GEMM: hc[chunk][N][64] = bf16(X @ W) chunk-major, MFMA ----------------
// 1D grid, chunk = blk&7 so chunk c lands on XCD c (same mapping as k_aggr2):
// the hc slice a given XCD writes is the slice it later gathers from.
__global__ __launch_bounds__(256) void k_gemm(const u16* __restrict__ Xbf,
                                              const u16* __restrict__ Wt,
                                              u16* __restrict__ hc) {
    const int blk = blockIdx.x;          // 313*8 blocks
    const int chunk = blk & 7;
    const int r0 = (blk >> 3) * 64;
    const int c0 = chunk * 64;
    __shared__ u16 As[64 * 136];  // +8 pad breaks 256B-stride bank aliasing
    __shared__ u16 Bs[64 * 136];
    const int t = threadIdx.x;
    for (int i = 0; i < 4; i++) {
        int flat = i * 256 + t;  // 1024 chunks of 8 u16
        int row = flat >> 4;
        int kc = flat & 15;
        uint4 av = make_uint4(0u, 0u, 0u, 0u);
        int gr = r0 + row;
        if (gr < N_NODES) av = *(const uint4*)(Xbf + gr * 128 + kc * 8);
        *(uint4*)(As + row * 136 + kc * 8) = av;
        uint4 bv = *(const uint4*)(Wt + (c0 + row) * 128 + kc * 8);
        *(uint4*)(Bs + row * 136 + kc * 8) = bv;
    }
    __syncthreads();
    const int wave = t >> 6, lane = t & 63;
    const int wr = (wave >> 1) * 32, wc = (wave & 1) * 32;
    const int lrow = lane & 15, quad = lane >> 4;
    f32x4 acc[2][2] = {};
    for (int kk = 0; kk < 128; kk += 32) {
        bf16x8 a[2], b[2];
        for (int mi = 0; mi < 2; mi++)
            a[mi] = *(const bf16x8*)(As + (wr + mi * 16 + lrow) * 136 + kk + quad * 8);
        for (int ni = 0; ni < 2; ni++)
            b[ni] = *(const bf16x8*)(Bs + (wc + ni * 16 + lrow) * 136 + kk + quad * 8);
        for (int mi = 0; mi < 2; mi++)
            for (int ni = 0; ni < 2; ni++)
                acc[mi][ni] = __builtin_amdgcn_mfma_f32_16x16x32_bf16(a[mi], b[ni], acc[mi][ni], 0, 0, 0);
    }
    u16* hslice = hc + (size_t)chunk * N_NODES * 64;
    for (int mi = 0; mi < 2; mi++)
        for (int ni = 0; ni < 2; ni++)
            for (int r = 0; r < 4; r++) {
                int row = r0 + wr + mi * 16 + quad * 4 + r;
                int col = wc + ni * 16 + lrow;  // within chunk [0,64)
                if (row < N_NODES) hslice[(size_t)row * 64 + col] = f2bf(acc[mi][ni][r]);
            }
}

// ---------------- attention logits: a_s/a_d[N][4] = X @ Vs/Vd (one wave per node) ----------------
__global__ __launch_bounds__(256) void k_att(const float* __restrict__ Xall, int layer,
                                             const float* __restrict__ Vs,
                                             const float* __restrict__ Vd,
                                             float* __restrict__ a_s, float* __restrict__ a_d) {
    int wid = (blockIdx.x * 256 + threadIdx.x) >> 6;  // node, grid exact
    int lane = threadIdx.x & 63;
    const float* Xr = Xall + wid * LSTRIDE + layer * 128;
    float x0 = Xr[lane], x1 = Xr[64 + lane];
    f32x4 vs0 = *(const f32x4*)(Vs + lane * 4), vs1 = *(const f32x4*)(Vs + (64 + lane) * 4);
    f32x4 vd0 = *(const f32x4*)(Vd + lane * 4), vd1 = *(const f32x4*)(Vd + (64 + lane) * 4);
    f32x4 ps = x0 * vs0 + x1 * vs1;
    f32x4 pd = x0 * vd0 + x1 * vd1;
    for (int off = 32; off; off >>= 1)
        for (int c = 0; c < 4; c++) {
            ps[c] += __shfl_xor(ps[c], off);
            pd[c] += __shfl_xor(pd[c], off);
        }
    if (lane == 0) {
        *(f32x4*)(a_s + wid * 4) = ps;
        *(f32x4*)(a_d + wid * 4) = pd;
    }
}

// ---------------- fused aggregation, XCD-chunked ----------------
// Block = (dst group of 4) x (channel chunk of 64). chunk = blk&7 -> pinned XCD,
// per-XCD gather working set = 2.56 MB (fits 4 MB L2).
// Single-pass softmax: acc += exp(e)*h ; den += exp(e) ; normalize at end.
// (max-subtraction dropped: logits are O(+-10), exp is safe in f32; ratio identical)
__global__ __launch_bounds__(256) void k_aggr2(
    const int* __restrict__ indptr, const int* __restrict__ esrc,
    const float* __restrict__ a_s, const float* __restrict__ a_d,
    const u16* __restrict__ hc, const float* __restrict__ bias,
    u16* __restrict__ Xbf, float* __restrict__ Xall, float* __restrict__ Yall, int layer) {
    const int blk = blockIdx.x;              // 5000*8 blocks
    const int chunk = blk & 7;
    const int grp = blk >> 3;
    const int wave = threadIdx.x >> 6;
    const int d = grp * 4 + wave;            // dst node, grid exact
    const int lane = threadIdx.x & 63;
    const int cl = lane & 15;                // channel-quad within chunk
    const int eg = lane >> 4;                // edge group (4 edges in flight)
    const int hd = chunk >> 1;               // head of this chunk
    const int start = indptr[d], end = indptr[d + 1];
    const float adh = a_d[d * 4 + hd];
    const u16* hslice = hc + (size_t)chunk * N_NODES * 64;

    f32x4 acc = {0.f, 0.f, 0.f, 0.f};
    float den = 0.f;
    for (int j0 = start; j0 < end; j0 += 4) {
        int j = j0 + eg;
        if (j < end) {
            int s = esrc[j];                              // broadcast within eg
            float e = a_s[s * 4 + hd] + adh;              // broadcast within eg
            e = e > 0.f ? e : NEG_SLOPE * e;
            float w = __expf(e);
            den += w;
            uint2 hv = *(const uint2*)(hslice + (size_t)s * 64 + cl * 4);  // 8B/lane
            acc[0] += w * __uint_as_float(hv.x << 16);
            acc[1] += w * __uint_as_float(hv.x & 0xffff0000u);
            acc[2] += w * __uint_as_float(hv.y << 16);
            acc[3] += w * __uint_as_float(hv.y & 0xffff0000u);
        }
    }
    // reduce across the 4 edge groups (lanes {cl, cl+16, cl+32, cl+48})
    for (int off = 16; off <= 32; off <<= 1) {
        for (int c = 0; c < 4; c++) acc[c] += __shfl_xor(acc[c], off);
        den += __shfl_xor(den, off);
    }
    if (eg == 0) {
        float rden = 1.f / den;               // self-loop => den >= exp(finite) > 0
        int gc = chunk * 64 + cl * 4;         // global head-major channel base
        f32x4 bv = *(const f32x4*)(bias + gc);
        float g[4];
        for (int i = 0; i < 4; i++) {
            float v = acc[i] * rden + bv[i];
            g[i] = v > 0.f ? v : __expf(v) - 1.f;  // elu
        }
        float agg = (g[0] + g[1] + g[2] + g[3]) * 0.25f;  // mean over 4 consecutive
        int k = chunk * 16 + cl;              // output channel in [0,128)
        int xo = d * LSTRIDE + layer * 128 + k;
        int no = d * LSTRIDE + (layer + 1) * 128 + k;
        float xprev = Xall[xo];
        Xall[no] = agg;                       // X2 = agg  (DT=ALPHA=GAMMA=1 identity)
        Yall[no] = agg - xprev;               // Y2 = agg - X_prev
        Xbf[d * 128 + k] = f2bf(agg);
    }
}

// ---------------- readout: out[N][40] = X_final @ Wr^T + br ----------------
__global__ __launch_bounds__(256) void k_out(const float* __restrict__ Xall,
                                             const float* __restrict__ Wr,
                                             const float* __restrict__ br,
                                             float* __restrict__ out) {
    __shared__ float Xs[4][128];
    int wave = threadIdx.x >> 6, lane = threadIdx.x & 63;
    int n = blockIdx.x * 4 + wave;  // grid exact: 5000 blocks
    const float* Xr = Xall + n * LSTRIDE + NLAYERS * 128;
    Xs[wave][lane] = Xr[lane];
    Xs[wave][64 + lane] = Xr[64 + lane];
    __syncthreads();
    if (lane < NCLASS) {
        float acc = 0.f;
        for (int kc = 0; kc < 32; kc++) {
            f32x4 wv = *(const f32x4*)(Wr + lane * 128 + kc * 4);
            for (int q = 0; q < 4; q++) acc += Xs[wave][kc * 4 + q] * wv[q];
        }
        out[n * NCLASS + lane] = acc + br[lane];
    }
}

extern "C" void kernel_launch(void* const* d_in, const int* in_sizes, int n_in,
                              void* d_out, int out_size, void* d_ws, size_t ws_size,
                              hipStream_t stream) {
    const float* x = (const float*)d_in[0];
    const int* src = (const int*)d_in[1];
    const int* dst = (const int*)d_in[2];
    const float* W = (const float*)d_in[3];
    const float* att_s = (const float*)d_in[4];
    const float* att_d = (const float*)d_in[5];
    const float* bias = (const float*)d_in[6];
    const float* Wr = (const float*)d_in[7];
    const float* br = (const float*)d_in[8];

    float* out = (float*)d_out;
    float* Xall = out + (size_t)N_NODES * NCLASS;
    float* Yall = Xall + (size_t)N_NODES * LSTRIDE;

    char* p = (char*)d_ws;
    auto alloc = [&](size_t bytes) -> char* {
        char* r = p;
        p += (bytes + 255) & ~(size_t)255;
        return r;
    };
    u16* Xbf = (u16*)alloc((size_t)N_NODES * 128 * 2);
    u16* hc = (u16*)alloc((size_t)8 * N_NODES * 64 * 2);
    u16* Wt = (u16*)alloc(512 * 128 * 2);
    float* a_s = (float*)alloc((size_t)N_NODES * 4 * 4);
    float* a_d = (float*)alloc((size_t)N_NODES * 4 * 4);
    float* Vs = (float*)alloc(128 * 4 * 4);
    float* Vd = (float*)alloc(128 * 4 * 4);
    int* indptr = (int*)alloc((N_NODES + 1) * 4);
    int* cursor = (int*)alloc(N_NODES * 4);
    int* counts = (int*)alloc(N_NODES * 4);
    int* esrc = (int*)alloc((size_t)(NE + N_NODES) * 4);

    k_init<<<(N_NODES * 128 + 255) / 256, 256, 0, stream>>>(x, Xbf, Xall, Yall);
    k_trans<<<(512 * 128) / 256, 256, 0, stream>>>(W, Wt);
    k_fold<<<1, 512, 0, stream>>>(W, att_s, att_d, Vs, Vd);
    k_ones<<<(N_NODES + 255) / 256, 256, 0, stream>>>(counts);
    k_count<<<(NE + 255) / 256, 256, 0, stream>>>(dst, counts);
    k_scan<<<1, 1024, 0, stream>>>(counts, indptr, cursor);
    k_scatter<<<(NE + N_NODES + 255) / 256, 256, 0, stream>>>(src, dst, cursor, esrc);

    for (int layer = 0; layer < NLAYERS; layer++) {
        k_gemm<<<313 * 8, 256, 0, stream>>>(Xbf, Wt, hc);
        k_att<<<N_NODES / 4, 256, 0, stream>>>(Xall, layer, Vs, Vd, a_s, a_d);
        k_aggr2<<<(N_NODES / 4) * 8, 256, 0, stream>>>(indptr, esrc, a_s, a_d, hc, bias,
                                                       Xbf, Xall, Yall, layer);
    }
    k_out<<<N_NODES / 4, 256, 0, stream>>>(Xall, Wr, br, out);
}

// Round 5
// 715.181 us; speedup vs baseline: 1.0646x; 1.0646x over previous
//
#include <hip/hip_runtime.h>

typedef unsigned short u16;
typedef unsigned int u32;

#define N_NODES 20000
#define NE 320000
#define NLAYERS 4
#define NCLASS 40
#define NEG_SLOPE 0.2f
#define LSTRIDE ((NLAYERS + 1) * 128)  // 640 floats per node in X_all/Y_all

typedef __bf16 bf16x8 __attribute__((ext_vector_type(8)));
typedef float f32x4 __attribute__((ext_vector_type(4)));

__device__ inline u16 f2bf(float f) {
    u32 u = __float_as_uint(f);
    return (u16)((u + 0x7fffu + ((u >> 16) & 1u)) >> 16);  // round-nearest-even
}
__device__ inline float bf_lo(u32 u) { return __uint_as_float(u << 16); }
__device__ inline float bf_hi(u32 u) { return __uint_as_float(u & 0xffff0000u); }

// ---------------- init: Xbf=bf16(x), X_all[:,0,:]=x, Y_all[:,0,:]=x (float4) ----------------
__global__ void k_init(const float* __restrict__ x, u16* __restrict__ Xbf,
                       float* __restrict__ Xall, float* __restrict__ Yall) {
    int t = blockIdx.x * 256 + threadIdx.x;  // t < 640000 float4's
    if (t >= N_NODES * 32) return;
    f32x4 v = ((const f32x4*)x)[t];
    u32 p0 = (u32)f2bf(v[0]) | ((u32)f2bf(v[1]) << 16);
    u32 p1 = (u32)f2bf(v[2]) | ((u32)f2bf(v[3]) << 16);
    ((uint2*)Xbf)[t] = make_uint2(p0, p1);
    int n = t >> 5, c4 = t & 31;             // 32 float4 per 128-ch row
    int ob = n * (LSTRIDE / 4) + c4;         // layer-0 slot
    ((f32x4*)Xall)[ob] = v;
    ((f32x4*)Yall)[ob] = v;
}

// ---------------- zero the counts array (avoid hipMemsetAsync in capture path) ----------------
__global__ void k_zero(int* __restrict__ counts) {
    int t = blockIdx.x * 256 + threadIdx.x;
    if (t < N_NODES) counts[t] = 0;
}

// ---------------- Wt[512][128] = bf16(W^T) ----------------
__global__ void k_trans(const float* __restrict__ W, u16* __restrict__ Wt) {
    int t = blockIdx.x * 256 + threadIdx.x;  // 65536 threads
    int k = t >> 9, col = t & 511;
    Wt[col * 128 + k] = f2bf(W[t]);
}

// ---------------- fold attention vectors through W: Vs/Vd[128][4] (f32, exact path) ----------------
__global__ void k_fold(const float* __restrict__ W, const float* __restrict__ att_s,
                       const float* __restrict__ att_d, float* __restrict__ Vs,
                       float* __restrict__ Vd) {
    int t = threadIdx.x;  // 512 threads: t = row*4 + hd
    int row = t >> 2, hd = t & 3;
    float s1 = 0.f, s2 = 0.f;
    for (int c = 0; c < 128; c++) {
        float w = W[row * 512 + hd * 128 + c];
        s1 += w * att_s[hd * 128 + c];
        s2 += w * att_d[hd * 128 + c];
    }
    Vs[t] = s1;
    Vd[t] = s2;
}

// ---------------- CSR build over dst (self loops added in scan/scatter) ----------------
__global__ void k_count(const int* __restrict__ dst, int* __restrict__ counts) {
    int t = blockIdx.x * 256 + threadIdx.x;
    if (t < NE) atomicAdd(&counts[dst[t]], 1);
}
__global__ void k_scan(const int* __restrict__ counts, int* __restrict__ indptr,
                       int* __restrict__ cursor) {
    __shared__ int part[1024];
    int t = threadIdx.x;
    const int CH = 20;  // 1024*20 >= 20000
    int c0 = t * CH;
    int s = 0;
    for (int i = 0; i < CH; i++) {
        int idx = c0 + i;
        if (idx < N_NODES) s += counts[idx] + 1;  // +1 self loop
    }
    part[t] = s;
    __syncthreads();
    for (int off = 1; off < 1024; off <<= 1) {
        int v = 0;
        if (t >= off) v = part[t - off];
        __syncthreads();
        if (t >= off) part[t] += v;
        __syncthreads();
    }
    int ex = (t == 0) ? 0 : part[t - 1];
    for (int i = 0; i < CH; i++) {
        int idx = c0 + i;
        if (idx < N_NODES) {
            indptr[idx] = ex;
            cursor[idx] = ex;
            ex += counts[idx] + 1;
        }
    }
    if (t == 1023) indptr[N_NODES] = part[1023];
}
__global__ void k_scatter(const int* __restrict__ src, const int* __restrict__ dst,
                          int* __restrict__ cursor, int* __restrict__ esrc) {
    int t = blockIdx.x * 256 + threadIdx.x;
    if (t >= NE + N_NODES) return;
    int s, d;
    if (t < NE) { s = src[t]; d = dst[t]; }
    else { s = d = t - NE; }
    int pos = atomicAdd(&cursor[d], 1);
    esrc[pos] = s;
}

// ---------------- GEMM: hc[chunk][N][64] = bf16(X @ W) chunk-major, MFMA ----------------
// chunk = blk&7 so chunk c lands on XCD c (same mapping as k_aggr3).
__global__ __launch_bounds__(256) void k_gemm(const u16* __restrict__ Xbf,
                                              const u16* __restrict__ Wt,
                                              u16* __restrict__ hc) {
    const int blk = blockIdx.x;          // 313*8 blocks
    const int chunk = blk & 7;
    const int r0 = (blk >> 3) * 64;
    const int c0 = chunk * 64;
    __shared__ u16 As[64 * 136];  // +8 pad breaks 256B-stride bank aliasing
    __shared__ u16 Bs[64 * 136];
    const int t = threadIdx.x;
    for (int i = 0; i < 4; i++) {
        int flat = i * 256 + t;  // 1024 chunks of 8 u16
        int row = flat >> 4;
        int kc = flat & 15;
        uint4 av = make_uint4(0u, 0u, 0u, 0u);
        int gr = r0 + row;
        if (gr < N_NODES) av = *(const uint4*)(Xbf + gr * 128 + kc * 8);
        *(uint4*)(As + row * 136 + kc * 8) = av;
        uint4 bv = *(const uint4*)(Wt + (c0 + row) * 128 + kc * 8);
        *(uint4*)(Bs + row * 136 + kc * 8) = bv;
    }
    __syncthreads();
    const int wave = t >> 6, lane = t & 63;
    const int wr = (wave >> 1) * 32, wc = (wave & 1) * 32;
    const int lrow = lane & 15, quad = lane >> 4;
    f32x4 acc[2][2] = {};
    for (int kk = 0; kk < 128; kk += 32) {
        bf16x8 a[2], b[2];
        for (int mi = 0; mi < 2; mi++)
            a[mi] = *(const bf16x8*)(As + (wr + mi * 16 + lrow) * 136 + kk + quad * 8);
        for (int ni = 0; ni < 2; ni++)
            b[ni] = *(const bf16x8*)(Bs + (wc + ni * 16 + lrow) * 136 + kk + quad * 8);
        for (int mi = 0; mi < 2; mi++)
            for (int ni = 0; ni < 2; ni++)
                acc[mi][ni] = __builtin_amdgcn_mfma_f32_16x16x32_bf16(a[mi], b[ni], acc[mi][ni], 0, 0, 0);
    }
    u16* hslice = hc + (size_t)chunk * N_NODES * 64;
    for (int mi = 0; mi < 2; mi++)
        for (int ni = 0; ni < 2; ni++)
            for (int r = 0; r < 4; r++) {
                int row = r0 + wr + mi * 16 + quad * 4 + r;
                int col = wc + ni * 16 + lrow;  // within chunk [0,64)
                if (row < N_NODES) hslice[(size_t)row * 64 + col] = f2bf(acc[mi][ni][r]);
            }
}

// ---------------- attention logits: a_s/a_d[N][4] = X @ Vs/Vd (one wave per node) ----------------
__global__ __launch_bounds__(256) void k_att(const float* __restrict__ Xall, int layer,
                                             const float* __restrict__ Vs,
                                             const float* __restrict__ Vd,
                                             float* __restrict__ a_s, float* __restrict__ a_d) {
    int wid = (blockIdx.x * 256 + threadIdx.x) >> 6;  // node, grid exact
    int lane = threadIdx.x & 63;
    const float* Xr = Xall + wid * LSTRIDE + layer * 128;
    float x0 = Xr[lane], x1 = Xr[64 + lane];
    f32x4 vs0 = *(const f32x4*)(Vs + lane * 4), vs1 = *(const f32x4*)(Vs + (64 + lane) * 4);
    f32x4 vd0 = *(const f32x4*)(Vd + lane * 4), vd1 = *(const f32x4*)(Vd + (64 + lane) * 4);
    f32x4 ps = x0 * vs0 + x1 * vs1;
    f32x4 pd = x0 * vd0 + x1 * vd1;
    for (int off = 32; off; off >>= 1)
        for (int c = 0; c < 4; c++) {
            ps[c] += __shfl_xor(ps[c], off);
            pd[c] += __shfl_xor(pd[c], off);
        }
    if (lane == 0) {
        *(f32x4*)(a_s + wid * 4) = ps;
        *(f32x4*)(a_d + wid * 4) = pd;
    }
}

// ---------------- per-edge weights: wE[j][4] = exp(leaky(a_s[s]+a_d[d])), rdenN[d][4] ----------------
// One wave per dst node; lanes stride the edge list. Single pass, no max-subtraction
// (logits are O(+-10): exp safe in f32, softmax ratio identical).
__global__ __launch_bounds__(256) void k_alpha(const int* __restrict__ indptr,
                                               const int* __restrict__ esrc,
                                               const float* __restrict__ a_s,
                                               const float* __restrict__ a_d,
                                               float* __restrict__ wE,
                                               float* __restrict__ rdenN) {
    int d = (blockIdx.x * 256 + threadIdx.x) >> 6;  // grid exact
    int lane = threadIdx.x & 63;
    int start = indptr[d], end = indptr[d + 1];
    f32x4 ad = *(const f32x4*)(a_d + d * 4);
    f32x4 den = {0.f, 0.f, 0.f, 0.f};
    for (int j = start + lane; j < end; j += 64) {
        int s = esrc[j];
        f32x4 e = *(const f32x4*)(a_s + s * 4) + ad;
        f32x4 w;
        for (int c = 0; c < 4; c++) {
            float v = e[c];
            v = v > 0.f ? v : NEG_SLOPE * v;
            w[c] = __expf(v);
            den[c] += w[c];
        }
        *(f32x4*)(wE + j * 4) = w;
    }
    for (int off = 32; off; off >>= 1)
        for (int c = 0; c < 4; c++) den[c] += __shfl_xor(den[c], off);
    if (lane == 0) {
        f32x4 r;
        for (int c = 0; c < 4; c++) r[c] = 1.f / den[c];
        *(f32x4*)(rdenN + d * 4) = r;
    }
}

// ---------------- aggregation, XCD-chunked, precomputed weights ----------------
// Block = (dst group of 4) x (channel chunk of 64); chunk = blk&7 -> pinned XCD,
// per-XCD gather working set 2.56 MB (fits 4 MB L2).
// Lane layout: eg = lane>>3 (8 edges in flight), cl = lane&7 (8 channels via uint4).
// Loop body: esrc[j] -> 16B h-gather, sequential wE stream, 8 FMA. All softmax
// scalar work (exp/leaky/a_s gather) precomputed by k_alpha.
__global__ __launch_bounds__(256) void k_aggr3(
    const int* __restrict__ indptr, const int* __restrict__ esrc,
    const float* __restrict__ wE, const float* __restrict__ rdenN,
    const u16* __restrict__ hc, const float* __restrict__ bias,
    u16* __restrict__ Xbf, float* __restrict__ Xall, float* __restrict__ Yall, int layer) {
    const int blk = blockIdx.x;              // 5000*8 blocks
    const int chunk = blk & 7;
    const int grp = blk >> 3;
    const int wave = threadIdx.x >> 6;
    const int d = grp * 4 + wave;            // dst node, grid exact
    const int lane = threadIdx.x & 63;
    const int cl = lane & 7;                 // channel octet within chunk
    const int eg = lane >> 3;                // edge group
    const int hd = chunk >> 1;               // head of this chunk
    const int start = indptr[d], end = indptr[d + 1];
    const u16* hslice = hc + (size_t)chunk * N_NODES * 64;

    float acc[8] = {0.f, 0.f, 0.f, 0.f, 0.f, 0.f, 0.f, 0.f};
    for (int j0 = start; j0 < end; j0 += 8) {
        int j = j0 + eg;
        if (j < end) {
            int s = esrc[j];
            float w = wE[j * 4 + hd];
            uint4 hv = *(const uint4*)(hslice + (size_t)s * 64 + cl * 8);  // 16B: 8 ch
            acc[0] += w * bf_lo(hv.x);
            acc[1] += w * bf_hi(hv.x);
            acc[2] += w * bf_lo(hv.y);
            acc[3] += w * bf_hi(hv.y);
            acc[4] += w * bf_lo(hv.z);
            acc[5] += w * bf_hi(hv.z);
            acc[6] += w * bf_lo(hv.w);
            acc[7] += w * bf_hi(hv.w);
        }
    }
    // reduce across 8 edge groups (lanes {cl, cl+8, ..., cl+56})
    for (int off = 8; off <= 32; off <<= 1)
        for (int c = 0; c < 8; c++) acc[c] += __shfl_xor(acc[c], off);
    if (eg == 0) {
        float rden = rdenN[d * 4 + hd];
        int gc = chunk * 64 + cl * 8;         // global head-major channel base
        f32x4 b0 = *(const f32x4*)(bias + gc);
        f32x4 b1 = *(const f32x4*)(bias + gc + 4);
        float g[8];
        for (int i = 0; i < 4; i++) g[i] = acc[i] * rden + b0[i];
        for (int i = 0; i < 4; i++) g[4 + i] = acc[4 + i] * rden + b1[i];
        for (int i = 0; i < 8; i++) {
            float v = g[i];
            g[i] = v > 0.f ? v : __expf(v) - 1.f;  // elu
        }
        float agg0 = (g[0] + g[1] + g[2] + g[3]) * 0.25f;  // mean over 4 consecutive
        float agg1 = (g[4] + g[5] + g[6] + g[7]) * 0.25f;
        int k = chunk * 16 + cl * 2;          // output channels k, k+1
        int xo = d * LSTRIDE + layer * 128 + k;
        int no = d * LSTRIDE + (layer + 1) * 128 + k;
        float x0 = Xall[xo], x1 = Xall[xo + 1];
        Xall[no] = agg0;                      // X2 = agg  (DT=ALPHA=GAMMA=1 identity)
        Xall[no + 1] = agg1;
        Yall[no] = agg0 - x0;                 // Y2 = agg - X_prev
        Yall[no + 1] = agg1 - x1;
        *(u32*)(Xbf + d * 128 + k) = (u32)f2bf(agg0) | ((u32)f2bf(agg1) << 16);
    }
}

// ---------------- readout: out[N][40] = X_final @ Wr^T + br ----------------
__global__ __launch_bounds__(256) void k_out(const float* __restrict__ Xall,
                                             const float* __restrict__ Wr,
                                             const float* __restrict__ br,
                                             float* __restrict__ out) {
    __shared__ float Xs[4][128];
    int wave = threadIdx.x >> 6, lane = threadIdx.x & 63;
    int n = blockIdx.x * 4 + wave;  // grid exact: 5000 blocks
    const float* Xr = Xall + n * LSTRIDE + NLAYERS * 128;
    Xs[wave][lane] = Xr[lane];
    Xs[wave][64 + lane] = Xr[64 + lane];
    __syncthreads();
    if (lane < NCLASS) {
        float acc = 0.f;
        for (int kc = 0; kc < 32; kc++) {
            f32x4 wv = *(const f32x4*)(Wr + lane * 128 + kc * 4);
            for (int q = 0; q < 4; q++) acc += Xs[wave][kc * 4 + q] * wv[q];
        }
        out[n * NCLASS + lane] = acc + br[lane];
    }
}

extern "C" void kernel_launch(void* const* d_in, const int* in_sizes, int n_in,
                              void* d_out, int out_size, void* d_ws, size_t ws_size,
                              hipStream_t stream) {
    const float* x = (const float*)d_in[0];
    const int* src = (const int*)d_in[1];
    const int* dst = (const int*)d_in[2];
    const float* W = (const float*)d_in[3];
    const float* att_s = (const float*)d_in[4];
    const float* att_d = (const float*)d_in[5];
    const float* bias = (const float*)d_in[6];
    const float* Wr = (const float*)d_in[7];
    const float* br = (const float*)d_in[8];

    float* out = (float*)d_out;
    float* Xall = out + (size_t)N_NODES * NCLASS;
    float* Yall = Xall + (size_t)N_NODES * LSTRIDE;

    char* p = (char*)d_ws;
    auto alloc = [&](size_t bytes) -> char* {
        char* r = p;
        p += (bytes + 255) & ~(size_t)255;
        return r;
    };
    u16* Xbf = (u16*)alloc((size_t)N_NODES * 128 * 2);
    u16* hc = (u16*)alloc((size_t)8 * N_NODES * 64 * 2);
    u16* Wt = (u16*)alloc(512 * 128 * 2);
    float* a_s = (float*)alloc((size_t)N_NODES * 4 * 4);
    float* a_d = (float*)alloc((size_t)N_NODES * 4 * 4);
    float* Vs = (float*)alloc(128 * 4 * 4);
    float* Vd = (float*)alloc(128 * 4 * 4);
    float* wE = (float*)alloc((size_t)(NE + N_NODES) * 4 * 4);
    float* rdenN = (float*)alloc((size_t)N_NODES * 4 * 4);
    int* indptr = (int*)alloc((N_NODES + 1) * 4);
    int* cursor = (int*)alloc(N_NODES * 4);
    int* counts = (int*)alloc(N_NODES * 4);
    int* esrc = (int*)alloc((size_t)(NE + N_NODES) * 4);

    k_init<<<(N_NODES * 32 + 255) / 256, 256, 0, stream>>>(x, Xbf, Xall, Yall);
    k_trans<<<(512 * 128) / 256, 256, 0, stream>>>(W, Wt);
    k_fold<<<1, 512, 0, stream>>>(W, att_s, att_d, Vs, Vd);
    k_zero<<<(N_NODES + 255) / 256, 256, 0, stream>>>(counts);
    k_count<<<(NE + 255) / 256, 256, 0, stream>>>(dst, counts);
    k_scan<<<1, 1024, 0, stream>>>(counts, indptr, cursor);
    k_scatter<<<(NE + N_NODES + 255) / 256, 256, 0, stream>>>(src, dst, cursor, esrc);

    for (int layer = 0; layer < NLAYERS; layer++) {
        k_gemm<<<313 * 8, 256, 0, stream>>>(Xbf, Wt, hc);
        k_att<<<N_NODES / 4, 256, 0, stream>>>(Xall, layer, Vs, Vd, a_s, a_d);
        k_alpha<<<N_NODES / 4, 256, 0, stream>>>(indptr, esrc, a_s, a_d, wE, rdenN);
        k_aggr3<<<(N_NODES / 4) * 8, 256, 0, stream>>>(indptr, esrc, wE, rdenN, hc, bias,
                                                       Xbf, Xall, Yall, layer);
    }
    k_out<<<N_NODES / 4, 256, 0, stream>>>(Xall, Wr, br, out);
}

// Round 6
// 704.970 us; speedup vs baseline: 1.0800x; 1.0145x over previous
//
#include <hip/hip_runtime.h>

typedef unsigned short u16;
typedef unsigned int u32;

#define N_NODES 20000
#define NE 320000
#define NLAYERS 4
#define NCLASS 40
#define NEG_SLOPE 0.2f
#define LSTRIDE ((NLAYERS + 1) * 128)  // 640 floats per node in X_all/Y_all
#define ESTRIDE (NE + N_NODES)         // 340000 edges incl self loops

typedef __bf16 bf16x8 __attribute__((ext_vector_type(8)));
typedef float f32x4 __attribute__((ext_vector_type(4)));

__device__ inline u16 f2bf(float f) {
    u32 u = __float_as_uint(f);
    return (u16)((u + 0x7fffu + ((u >> 16) & 1u)) >> 16);  // round-nearest-even
}
__device__ inline float bf_lo(u32 u) { return __uint_as_float(u << 16); }
__device__ inline float bf_hi(u32 u) { return __uint_as_float(u & 0xffff0000u); }

// ---------------- init: Xbf=bf16(x), X_all[:,0,:]=x, Y_all[:,0,:]=x (float4) ----------------
__global__ void k_init(const float* __restrict__ x, u16* __restrict__ Xbf,
                       float* __restrict__ Xall, float* __restrict__ Yall) {
    int t = blockIdx.x * 256 + threadIdx.x;  // t < 640000 float4's
    if (t >= N_NODES * 32) return;
    f32x4 v = ((const f32x4*)x)[t];
    u32 p0 = (u32)f2bf(v[0]) | ((u32)f2bf(v[1]) << 16);
    u32 p1 = (u32)f2bf(v[2]) | ((u32)f2bf(v[3]) << 16);
    ((uint2*)Xbf)[t] = make_uint2(p0, p1);
    int n = t >> 5, c4 = t & 31;             // 32 float4 per 128-ch row
    int ob = n * (LSTRIDE / 4) + c4;         // layer-0 slot
    ((f32x4*)Xall)[ob] = v;
    ((f32x4*)Yall)[ob] = v;
}

// ---------------- zero the counts array (avoid hipMemsetAsync in capture path) ----------------
__global__ void k_zero(int* __restrict__ counts) {
    int t = blockIdx.x * 256 + threadIdx.x;
    if (t < N_NODES) counts[t] = 0;
}

// ---------------- Wt[512][128] = bf16(W^T) ----------------
__global__ void k_trans(const float* __restrict__ W, u16* __restrict__ Wt) {
    int t = blockIdx.x * 256 + threadIdx.x;  // 65536 threads
    int k = t >> 9, col = t & 511;
    Wt[col * 128 + k] = f2bf(W[t]);
}

// ---------------- fold attention vectors through W: Vs/Vd[128][4] (f32, exact path) ----------------
__global__ void k_fold(const float* __restrict__ W, const float* __restrict__ att_s,
                       const float* __restrict__ att_d, float* __restrict__ Vs,
                       float* __restrict__ Vd) {
    int t = threadIdx.x;  // 512 threads: t = row*4 + hd
    int row = t >> 2, hd = t & 3;
    float s1 = 0.f, s2 = 0.f;
    for (int c = 0; c < 128; c++) {
        float w = W[row * 512 + hd * 128 + c];
        s1 += w * att_s[hd * 128 + c];
        s2 += w * att_d[hd * 128 + c];
    }
    Vs[t] = s1;
    Vd[t] = s2;
}

// ---------------- CSR build over dst (self loops added in scan/scatter) ----------------
__global__ void k_count(const int* __restrict__ dst, int* __restrict__ counts) {
    int t = blockIdx.x * 256 + threadIdx.x;
    if (t < NE) atomicAdd(&counts[dst[t]], 1);
}
__global__ void k_scan(const int* __restrict__ counts, int* __restrict__ indptr,
                       int* __restrict__ cursor) {
    __shared__ int part[1024];
    int t = threadIdx.x;
    const int CH = 20;  // 1024*20 >= 20000
    int c0 = t * CH;
    int s = 0;
    for (int i = 0; i < CH; i++) {
        int idx = c0 + i;
        if (idx < N_NODES) s += counts[idx] + 1;  // +1 self loop
    }
    part[t] = s;
    __syncthreads();
    for (int off = 1; off < 1024; off <<= 1) {
        int v = 0;
        if (t >= off) v = part[t - off];
        __syncthreads();
        if (t >= off) part[t] += v;
        __syncthreads();
    }
    int ex = (t == 0) ? 0 : part[t - 1];
    for (int i = 0; i < CH; i++) {
        int idx = c0 + i;
        if (idx < N_NODES) {
            indptr[idx] = ex;
            cursor[idx] = ex;
            ex += counts[idx] + 1;
        }
    }
    if (t == 1023) indptr[N_NODES] = part[1023];
}
__global__ void k_scatter(const int* __restrict__ src, const int* __restrict__ dst,
                          int* __restrict__ cursor, int* __restrict__ esrc) {
    int t = blockIdx.x * 256 + threadIdx.x;
    if (t >= NE + N_NODES) return;
    int s, d;
    if (t < NE) { s = src[t]; d = dst[t]; }
    else { s = d = t - NE; }
    int pos = atomicAdd(&cursor[d], 1);
    esrc[pos] = s;
}

// ---------------- GEMM: hc[chunk][N][64] = bf16(X @ W) chunk-major, MFMA ----------------
// chunk = blk&7 so chunk c lands on XCD c (same mapping as k_aggr4).
__global__ __launch_bounds__(256) void k_gemm(const u16* __restrict__ Xbf,
                                              const u16* __restrict__ Wt,
                                              u16* __restrict__ hc) {
    const int blk = blockIdx.x;          // 313*8 blocks
    const int chunk = blk & 7;
    const int r0 = (blk >> 3) * 64;
    const int c0 = chunk * 64;
    __shared__ u16 As[64 * 136];  // +8 pad breaks 256B-stride bank aliasing
    __shared__ u16 Bs[64 * 136];
    const int t = threadIdx.x;
    for (int i = 0; i < 4; i++) {
        int flat = i * 256 + t;  // 1024 chunks of 8 u16
        int row = flat >> 4;
        int kc = flat & 15;
        uint4 av = make_uint4(0u, 0u, 0u, 0u);
        int gr = r0 + row;
        if (gr < N_NODES) av = *(const uint4*)(Xbf + gr * 128 + kc * 8);
        *(uint4*)(As + row * 136 + kc * 8) = av;
        uint4 bv = *(const uint4*)(Wt + (c0 + row) * 128 + kc * 8);
        *(uint4*)(Bs + row * 136 + kc * 8) = bv;
    }
    __syncthreads();
    const int wave = t >> 6, lane = t & 63;
    const int wr = (wave >> 1) * 32, wc = (wave & 1) * 32;
    const int lrow = lane & 15, quad = lane >> 4;
    f32x4 acc[2][2] = {};
    for (int kk = 0; kk < 128; kk += 32) {
        bf16x8 a[2], b[2];
        for (int mi = 0; mi < 2; mi++)
            a[mi] = *(const bf16x8*)(As + (wr + mi * 16 + lrow) * 136 + kk + quad * 8);
        for (int ni = 0; ni < 2; ni++)
            b[ni] = *(const bf16x8*)(Bs + (wc + ni * 16 + lrow) * 136 + kk + quad * 8);
        for (int mi = 0; mi < 2; mi++)
            for (int ni = 0; ni < 2; ni++)
                acc[mi][ni] = __builtin_amdgcn_mfma_f32_16x16x32_bf16(a[mi], b[ni], acc[mi][ni], 0, 0, 0);
    }
    u16* hslice = hc + (size_t)chunk * N_NODES * 64;
    for (int mi = 0; mi < 2; mi++)
        for (int ni = 0; ni < 2; ni++)
            for (int r = 0; r < 4; r++) {
                int row = r0 + wr + mi * 16 + quad * 4 + r;
                int col = wc + ni * 16 + lrow;  // within chunk [0,64)
                if (row < N_NODES) hslice[(size_t)row * 64 + col] = f2bf(acc[mi][ni][r]);
            }
}

// ---------------- attention logits: a_s/a_d[N][4] = X @ Vs/Vd (one wave per node) ----------------
__global__ __launch_bounds__(256) void k_att(const float* __restrict__ Xall, int layer,
                                             const float* __restrict__ Vs,
                                             const float* __restrict__ Vd,
                                             float* __restrict__ a_s, float* __restrict__ a_d) {
    int wid = (blockIdx.x * 256 + threadIdx.x) >> 6;  // node, grid exact
    int lane = threadIdx.x & 63;
    const float* Xr = Xall + wid * LSTRIDE + layer * 128;
    float x0 = Xr[lane], x1 = Xr[64 + lane];
    f32x4 vs0 = *(const f32x4*)(Vs + lane * 4), vs1 = *(const f32x4*)(Vs + (64 + lane) * 4);
    f32x4 vd0 = *(const f32x4*)(Vd + lane * 4), vd1 = *(const f32x4*)(Vd + (64 + lane) * 4);
    f32x4 ps = x0 * vs0 + x1 * vs1;
    f32x4 pd = x0 * vd0 + x1 * vd1;
    for (int off = 32; off; off >>= 1)
        for (int c = 0; c < 4; c++) {
            ps[c] += __shfl_xor(ps[c], off);
            pd[c] += __shfl_xor(pd[c], off);
        }
    if (lane == 0) {
        *(f32x4*)(a_s + wid * 4) = ps;
        *(f32x4*)(a_d + wid * 4) = pd;
    }
}

// ---------------- per-edge packed streams: ewh[head][j] = src | bf16(w)<<16 ----------------
// w = exp(leaky(a_s[s]+a_d[d])); den accumulated from the bf16-ROUNDED w so the
// normalization in k_aggr4 is numerically self-consistent. One wave per dst node.
// No max-subtraction (logits O(+-10): exp safe in f32, softmax ratio identical).
__global__ __launch_bounds__(256) void k_alpha(const int* __restrict__ indptr,
                                               const int* __restrict__ esrc,
                                               const float* __restrict__ a_s,
                                               const float* __restrict__ a_d,
                                               u32* __restrict__ ewh,
                                               float* __restrict__ rdenN) {
    int d = (blockIdx.x * 256 + threadIdx.x) >> 6;  // grid exact
    int lane = threadIdx.x & 63;
    int start = indptr[d], end = indptr[d + 1];
    f32x4 ad = *(const f32x4*)(a_d + d * 4);
    f32x4 den = {0.f, 0.f, 0.f, 0.f};
    for (int j = start + lane; j < end; j += 64) {
        u32 s = (u32)esrc[j];
        f32x4 e = *(const f32x4*)(a_s + s * 4) + ad;
        for (int c = 0; c < 4; c++) {
            float v = e[c];
            v = v > 0.f ? v : NEG_SLOPE * v;
            u32 wb = (u32)f2bf(__expf(v)) << 16;
            den[c] += __uint_as_float(wb);           // rounded w
            ewh[c * ESTRIDE + j] = s | wb;           // packed (src, bf16 w)
        }
    }
    for (int off = 32; off; off >>= 1)
        for (int c = 0; c < 4; c++) den[c] += __shfl_xor(den[c], off);
    if (lane == 0) {
        f32x4 r;
        for (int c = 0; c < 4; c++) r[c] = 1.f / den[c];
        *(f32x4*)(rdenN + d * 4) = r;
    }
}

// ---------------- aggregation, XCD-chunked, packed edge stream ----------------
// Block = (dst group of 4) x (channel chunk of 64); chunk = blk&7 -> pinned XCD,
// per-XCD gather working set 2.56 MB hc slice + 1.36 MB head stream (fits 4 MB L2).
// Lane layout: eg = lane>>3 (8 edges in flight), cl = lane&7 (8 channels via uint4).
// Loop body is BRANCHLESS: one sequential 4B packed load (src|w), one 16B gather,
// 8 FMA. OOB tail lanes read ew=0 -> w=0 contributes nothing (s=0 gather safe).
__global__ __launch_bounds__(256) void k_aggr4(
    const int* __restrict__ indptr, const u32* __restrict__ ewh,
    const float* __restrict__ rdenN,
    const u16* __restrict__ hc, const float* __restrict__ bias,
    u16* __restrict__ Xbf, float* __restrict__ Xall, float* __restrict__ Yall, int layer) {
    const int blk = blockIdx.x;              // 5000*8 blocks
    const int chunk = blk & 7;
    const int grp = blk >> 3;
    const int wave = threadIdx.x >> 6;
    const int d = grp * 4 + wave;            // dst node, grid exact
    const int lane = threadIdx.x & 63;
    const int cl = lane & 7;                 // channel octet within chunk
    const int eg = lane >> 3;                // edge group
    const int hd = chunk >> 1;               // head of this chunk
    const int start = indptr[d], end = indptr[d + 1];
    const u16* hslice = hc + (size_t)chunk * N_NODES * 64;
    const u32* estream = ewh + (size_t)hd * ESTRIDE;

    float acc[8] = {0.f, 0.f, 0.f, 0.f, 0.f, 0.f, 0.f, 0.f};
    for (int j0 = start; j0 < end; j0 += 8) {
        int j = j0 + eg;
        u32 ew = (j < end) ? estream[j] : 0u;
        u32 s = ew & 0xffffu;
        float w = bf_hi(ew);                 // bf16 weight in high half
        uint4 hv = *(const uint4*)(hslice + (size_t)s * 64 + cl * 8);  // 16B: 8 ch
        acc[0] += w * bf_lo(hv.x);
        acc[1] += w * bf_hi(hv.x);
        acc[2] += w * bf_lo(hv.y);
        acc[3] += w * bf_hi(hv.y);
        acc[4] += w * bf_lo(hv.z);
        acc[5] += w * bf_hi(hv.z);
        acc[6] += w * bf_lo(hv.w);
        acc[7] += w * bf_hi(hv.w);
    }
    // reduce across 8 edge groups (lanes {cl, cl+8, ..., cl+56})
    for (int off = 8; off <= 32; off <<= 1)
        for (int c = 0; c < 8; c++) acc[c] += __shfl_xor(acc[c], off);
    if (eg == 0) {
        float rden = rdenN[d * 4 + hd];
        int gc = chunk * 64 + cl * 8;         // global head-major channel base
        f32x4 b0 = *(const f32x4*)(bias + gc);
        f32x4 b1 = *(const f32x4*)(bias + gc + 4);
        float g[8];
        for (int i = 0; i < 4; i++) g[i] = acc[i] * rden + b0[i];
        for (int i = 0; i < 4; i++) g[4 + i] = acc[4 + i] * rden + b1[i];
        for (int i = 0; i < 8; i++) {
            float v = g[i];
            g[i] = v > 0.f ? v : __expf(v) - 1.f;  // elu
        }
        float agg0 = (g[0] + g[1] + g[2] + g[3]) * 0.25f;  // mean over 4 consecutive
        float agg1 = (g[4] + g[5] + g[6] + g[7]) * 0.25f;
        int k = chunk * 16 + cl * 2;          // output channels k, k+1
        int xo = d * LSTRIDE + layer * 128 + k;
        int no = d * LSTRIDE + (layer + 1) * 128 + k;
        float x0 = Xall[xo], x1 = Xall[xo + 1];
        Xall[no] = agg0;                      // X2 = agg  (DT=ALPHA=GAMMA=1 identity)
        Xall[no + 1] = agg1;
        Yall[no] = agg0 - x0;                 // Y2 = agg - X_prev
        Yall[no + 1] = agg1 - x1;
        *(u32*)(Xbf + d * 128 + k) = (u32)f2bf(agg0) | ((u32)f2bf(agg1) << 16);
    }
}

// ---------------- readout: out[N][40] = X_final @ Wr^T + br ----------------
__global__ __launch_bounds__(256) void k_out(const float* __restrict__ Xall,
                                             const float* __restrict__ Wr,
                                             const float* __restrict__ br,
                                             float* __restrict__ out) {
    __shared__ float Xs[4][128];
    int wave = threadIdx.x >> 6, lane = threadIdx.x & 63;
    int n = blockIdx.x * 4 + wave;  // grid exact: 5000 blocks
    const float* Xr = Xall + n * LSTRIDE + NLAYERS * 128;
    Xs[wave][lane] = Xr[lane];
    Xs[wave][64 + lane] = Xr[64 + lane];
    __syncthreads();
    if (lane < NCLASS) {
        float acc = 0.f;
        for (int kc = 0; kc < 32; kc++) {
            f32x4 wv = *(const f32x4*)(Wr + lane * 128 + kc * 4);
            for (int q = 0; q < 4; q++) acc += Xs[wave][kc * 4 + q] * wv[q];
        }
        out[n * NCLASS + lane] = acc + br[lane];
    }
}

extern "C" void kernel_launch(void* const* d_in, const int* in_sizes, int n_in,
                              void* d_out, int out_size, void* d_ws, size_t ws_size,
                              hipStream_t stream) {
    const float* x = (const float*)d_in[0];
    const int* src = (const int*)d_in[1];
    const int* dst = (const int*)d_in[2];
    const float* W = (const float*)d_in[3];
    const float* att_s = (const float*)d_in[4];
    const float* att_d = (const float*)d_in[5];
    const float* bias = (const float*)d_in[6];
    const float* Wr = (const float*)d_in[7];
    const float* br = (const float*)d_in[8];

    float* out = (float*)d_out;
    float* Xall = out + (size_t)N_NODES * NCLASS;
    float* Yall = Xall + (size_t)N_NODES * LSTRIDE;

    char* p = (char*)d_ws;
    auto alloc = [&](size_t bytes) -> char* {
        char* r = p;
        p += (bytes + 255) & ~(size_t)255;
        return r;
    };
    u16* Xbf = (u16*)alloc((size_t)N_NODES * 128 * 2);
    u16* hc = (u16*)alloc((size_t)8 * N_NODES * 64 * 2);
    u16* Wt = (u16*)alloc(512 * 128 * 2);
    float* a_s = (float*)alloc((size_t)N_NODES * 4 * 4);
    float* a_d = (float*)alloc((size_t)N_NODES * 4 * 4);
    float* Vs = (float*)alloc(128 * 4 * 4);
    float* Vd = (float*)alloc(128 * 4 * 4);
    u32* ewh = (u32*)alloc((size_t)4 * ESTRIDE * 4);
    float* rdenN = (float*)alloc((size_t)N_NODES * 4 * 4);
    int* indptr = (int*)alloc((N_NODES + 1) * 4);
    int* cursor = (int*)alloc(N_NODES * 4);
    int* counts = (int*)alloc(N_NODES * 4);
    int* esrc = (int*)alloc((size_t)ESTRIDE * 4);

    k_init<<<(N_NODES * 32 + 255) / 256, 256, 0, stream>>>(x, Xbf, Xall, Yall);
    k_trans<<<(512 * 128) / 256, 256, 0, stream>>>(W, Wt);
    k_fold<<<1, 512, 0, stream>>>(W, att_s, att_d, Vs, Vd);
    k_zero<<<(N_NODES + 255) / 256, 256, 0, stream>>>(counts);
    k_count<<<(NE + 255) / 256, 256, 0, stream>>>(dst, counts);
    k_scan<<<1, 1024, 0, stream>>>(counts, indptr, cursor);
    k_scatter<<<(NE + N_NODES + 255) / 256, 256, 0, stream>>>(src, dst, cursor, esrc);

    for (int layer = 0; layer < NLAYERS; layer++) {
        k_gemm<<<313 * 8, 256, 0, stream>>>(Xbf, Wt, hc);
        k_att<<<N_NODES / 4, 256, 0, stream>>>(Xall, layer, Vs, Vd, a_s, a_d);
        k_alpha<<<N_NODES / 4, 256, 0, stream>>>(indptr, esrc, a_s, a_d, ewh, rdenN);
        k_aggr4<<<(N_NODES / 4) * 8, 256, 0, stream>>>(indptr, ewh, rdenN, hc, bias,
                                                       Xbf, Xall, Yall, layer);
    }
    k_out<<<N_NODES / 4, 256, 0, stream>>>(Xall, Wr, br, out);
}